// Round 1
// baseline (3748.848 us; speedup 1.0000x reference)
//
#include <hip/hip_runtime.h>
#include <hip/hip_bf16.h>
#include <math.h>

// ---------------------------------------------------------------------------
// GCN 3-layer forward, fp32 baseline.
// Pipeline per layer: h = x @ W  (tiled fp32 GEMM)
//                     agg[i] = (1/deg[i]) * h[i]                (self loop)
//                     agg[dst] += dis[src]*dis[dst] * h[src]    (atomic scatter)
//                     x = relu(agg + b)      (layers 1,2)
//                     out = log_softmax(agg + b3)               (layer 3)
// ---------------------------------------------------------------------------

__global__ void k_deg_init(float* deg, int n) {
    int i = blockIdx.x * 256 + threadIdx.x;
    if (i < n) deg[i] = 1.0f;            // self loop contributes 1
}

__global__ void k_deg_count(const int* __restrict__ dst, float* deg, int e) {
    int i = blockIdx.x * 256 + threadIdx.x;
    if (i < e) atomicAdd(&deg[dst[i]], 1.0f);
}

__global__ void k_dis(const float* __restrict__ deg, float* dis, int n) {
    int i = blockIdx.x * 256 + threadIdx.x;
    if (i < n) dis[i] = rsqrtf(deg[i]);  // deg >= 1 always (self loop)
}

// Tiled fp32 GEMM: C[n x F] = A[n x K] @ W[K x F].  BN == F (full width per block).
// 256 threads, BM=128 rows/block, 8xTN register blocking.
template <int K, int F, int TN>
__global__ __launch_bounds__(256) void k_gemm(const float* __restrict__ A,
                                              const float* __restrict__ W,
                                              float* __restrict__ C, int n) {
    constexpr int BM = 128, BK = 16;
    constexpr int TCOLS = F / TN;       // 16
    constexpr int TM = BM / (256 / TCOLS);  // 8
    __shared__ float As[BK][BM];        // A tile, transposed (k-major)
    __shared__ float Ws[BK][F];

    const int tid = threadIdx.x;
    const int row0 = blockIdx.x * BM;
    const int tcol = (tid % TCOLS) * TN;
    const int trow = (tid / TCOLS) * TM;

    float acc[TM][TN] = {};

    for (int k0 = 0; k0 < K; k0 += BK) {
        // Stage A tile (transposed): 128x16 floats, 2 float4 per thread
#pragma unroll
        for (int l = 0; l < (BM * BK) / (256 * 4); ++l) {
            int idx = tid + l * 256;        // float4 index 0..511
            int r = idx / (BK / 4);
            int kq = (idx % (BK / 4)) * 4;
            float4 v = make_float4(0.f, 0.f, 0.f, 0.f);
            int gr = row0 + r;
            if (gr < n) v = *(const float4*)&A[(size_t)gr * K + k0 + kq];
            As[kq + 0][r] = v.x; As[kq + 1][r] = v.y;
            As[kq + 2][r] = v.z; As[kq + 3][r] = v.w;
        }
        // Stage W tile: BKxF floats
#pragma unroll
        for (int l = 0; l < (BK * F) / (256 * 4); ++l) {
            int idx = tid + l * 256;
            int k = idx / (F / 4);
            int c = (idx % (F / 4)) * 4;
            *(float4*)&Ws[k][c] = *(const float4*)&W[(size_t)(k0 + k) * F + c];
        }
        __syncthreads();
#pragma unroll
        for (int k = 0; k < BK; ++k) {
            float a[TM], w[TN];
#pragma unroll
            for (int i = 0; i < TM; ++i) a[i] = As[k][trow + i];
#pragma unroll
            for (int j = 0; j < TN; ++j) w[j] = Ws[k][tcol + j];
#pragma unroll
            for (int i = 0; i < TM; ++i)
#pragma unroll
                for (int j = 0; j < TN; ++j) acc[i][j] += a[i] * w[j];
        }
        __syncthreads();
    }
#pragma unroll
    for (int i = 0; i < TM; ++i) {
        int gr = row0 + trow + i;
        if (gr < n) {
#pragma unroll
            for (int j = 0; j < TN; j += 4)
                *(float4*)&C[(size_t)gr * F + tcol + j] = *(float4*)&acc[i][j];
        }
    }
}

// agg[i] = h[i] * dis[i]^2   (self-loop term; also serves as zero-init)
template <int F>
__global__ void k_selfinit(const float* __restrict__ h, const float* __restrict__ dis,
                           float* __restrict__ out, int n) {
    int gid = blockIdx.x * 256 + threadIdx.x;
    if (gid >= n * (F / 4)) return;
    int i = gid / (F / 4);
    int c = (gid % (F / 4)) * 4;
    float s = dis[i] * dis[i];
    float4 v = *(const float4*)&h[(size_t)i * F + c];
    v.x *= s; v.y *= s; v.z *= s; v.w *= s;
    *(float4*)&out[(size_t)i * F + c] = v;
}

// agg[dst] += dis[src]*dis[dst] * h[src]   one thread per (edge, 4 features)
template <int F>
__global__ void k_scatter(const int* __restrict__ src, const int* __restrict__ dst,
                          const float* __restrict__ dis, const float* __restrict__ h,
                          float* __restrict__ out, int e) {
    constexpr int PER = F / 4;
    int gid = blockIdx.x * 256 + threadIdx.x;
    if (gid >= e * PER) return;
    int ei = gid / PER;
    int c = (gid % PER) * 4;
    int s = src[ei], d = dst[ei];
    float nrm = dis[s] * dis[d];
    float4 hv = *(const float4*)&h[(size_t)s * F + c];
    float* o = &out[(size_t)d * F + c];
    atomicAdd(o + 0, hv.x * nrm);
    atomicAdd(o + 1, hv.y * nrm);
    atomicAdd(o + 2, hv.z * nrm);
    atomicAdd(o + 3, hv.w * nrm);
}

// x = relu(x + b)  in place
template <int F>
__global__ void k_bias_relu(float* __restrict__ x, const float* __restrict__ b, int n) {
    int gid = blockIdx.x * 256 + threadIdx.x;
    if (gid >= n * (F / 4)) return;
    int c = (gid % (F / 4)) * 4;
    float4 v = *(float4*)&x[(size_t)gid * 4];
    v.x = fmaxf(v.x + b[c + 0], 0.f);
    v.y = fmaxf(v.y + b[c + 1], 0.f);
    v.z = fmaxf(v.z + b[c + 2], 0.f);
    v.w = fmaxf(v.w + b[c + 3], 0.f);
    *(float4*)&x[(size_t)gid * 4] = v;
}

// out = log_softmax(x + b), one 64-lane wave per node (OUT_DIM = 64)
__global__ void k_logsoftmax64(const float* __restrict__ x, const float* __restrict__ b,
                               float* __restrict__ out, int n) {
    int lane = threadIdx.x & 63;
    int node = (blockIdx.x * blockDim.x + threadIdx.x) >> 6;
    if (node >= n) return;
    float v = x[(size_t)node * 64 + lane] + b[lane];
    float m = v;
#pragma unroll
    for (int s = 32; s; s >>= 1) m = fmaxf(m, __shfl_xor(m, s));
    float e = expf(v - m);
    float sum = e;
#pragma unroll
    for (int s = 32; s; s >>= 1) sum += __shfl_xor(sum, s);
    out[(size_t)node * 64 + lane] = (v - m) - logf(sum);
}

extern "C" void kernel_launch(void* const* d_in, const int* in_sizes, int n_in,
                              void* d_out, int out_size, void* d_ws, size_t ws_size,
                              hipStream_t stream) {
    constexpr int IN = 512, HID = 128, OUT = 64;
    const float* feats = (const float*)d_in[0];
    const int*   adj   = (const int*)d_in[1];
    const float* W1 = (const float*)d_in[2];
    const float* b1 = (const float*)d_in[3];
    const float* W2 = (const float*)d_in[4];
    const float* b2 = (const float*)d_in[5];
    const float* W3 = (const float*)d_in[6];
    const float* b3 = (const float*)d_in[7];
    float* out = (float*)d_out;

    const int n = in_sizes[0] / IN;      // 50000
    const int e = in_sizes[1] / 2;       // 800000
    const int* srcp = adj;
    const int* dstp = adj + e;

    // workspace layout (floats)
    float* deg  = (float*)d_ws;
    float* dis  = deg + n;
    float* bufh = dis + n;                       // n x 128 (GEMM out)
    float* bufx = bufh + (size_t)n * HID;        // n x 128 (aggregated / next input)

    const int nb_n   = (n + 255) / 256;
    const int nb_e   = (e + 255) / 256;
    const int nb_g   = (n + 127) / 128;          // GEMM blocks
    const int nb_eh  = (e * (HID / 4) + 255) / 256;
    const int nb_eo  = (e * (OUT / 4) + 255) / 256;
    const int nb_nh  = (n * (HID / 4) + 255) / 256;
    const int nb_no  = (n * (OUT / 4) + 255) / 256;

    // degrees & symmetric norm
    k_deg_init<<<nb_n, 256, 0, stream>>>(deg, n);
    k_deg_count<<<nb_e, 256, 0, stream>>>(dstp, deg, e);
    k_dis<<<nb_n, 256, 0, stream>>>(deg, dis, n);

    // ---- layer 1: 512 -> 128, relu
    k_gemm<IN, HID, 8><<<nb_g, 256, 0, stream>>>(feats, W1, bufh, n);
    k_selfinit<HID><<<nb_nh, 256, 0, stream>>>(bufh, dis, bufx, n);
    k_scatter<HID><<<nb_eh, 256, 0, stream>>>(srcp, dstp, dis, bufh, bufx, e);
    k_bias_relu<HID><<<nb_nh, 256, 0, stream>>>(bufx, b1, n);

    // ---- layer 2: 128 -> 128, relu
    k_gemm<HID, HID, 8><<<nb_g, 256, 0, stream>>>(bufx, W2, bufh, n);
    k_selfinit<HID><<<nb_nh, 256, 0, stream>>>(bufh, dis, bufx, n);
    k_scatter<HID><<<nb_eh, 256, 0, stream>>>(srcp, dstp, dis, bufh, bufx, e);
    k_bias_relu<HID><<<nb_nh, 256, 0, stream>>>(bufx, b2, n);

    // ---- layer 3: 128 -> 64, log_softmax
    k_gemm<HID, OUT, 4><<<nb_g, 256, 0, stream>>>(bufx, W3, bufh, n);
    k_selfinit<OUT><<<nb_no, 256, 0, stream>>>(bufh, dis, bufx, n);
    k_scatter<OUT><<<nb_eo, 256, 0, stream>>>(srcp, dstp, dis, bufh, bufx, e);
    k_logsoftmax64<<<(n * 64 + 255) / 256, 256, 0, stream>>>(bufx, b3, out, n);
}

// Round 2
// 691.615 us; speedup vs baseline: 5.4204x; 5.4204x over previous
//
#include <hip/hip_runtime.h>
#include <hip/hip_bf16.h>
#include <math.h>

// ---------------------------------------------------------------------------
// GCN 3-layer forward. R2: COO -> CSR on device, per-node GATHER aggregation
// (zero float atomics), with bias+relu / log_softmax fused into the gather.
// Per layer: h = x @ W (tiled fp32 GEMM); x' = gather(h) + epilogue.
// ---------------------------------------------------------------------------

__global__ void k_zero_i32(int* p, int n) {
    int i = blockIdx.x * 256 + threadIdx.x;
    if (i < n) p[i] = 0;
}

__global__ void k_deg_count(const int* __restrict__ dst, int* deg, int e) {
    int i = blockIdx.x * 256 + threadIdx.x;
    if (i < e) atomicAdd(&deg[dst[i]], 1);
}

__global__ void k_dis(const int* __restrict__ deg, float* dis, int n) {
    int i = blockIdx.x * 256 + threadIdx.x;
    if (i < n) dis[i] = rsqrtf((float)(deg[i] + 1));   // +1 self loop
}

// ---- 2-level exclusive scan over deg (n <= 65536: nblocks <= 256) ----
__global__ void k_scan_block(const int* __restrict__ deg, int* incl, int* bsum, int n) {
    __shared__ int s[256];
    int tid = threadIdx.x;
    int i = blockIdx.x * 256 + tid;
    int v = (i < n) ? deg[i] : 0;
    s[tid] = v;
    __syncthreads();
    for (int off = 1; off < 256; off <<= 1) {
        int t = (tid >= off) ? s[tid - off] : 0;
        __syncthreads();
        s[tid] += t;
        __syncthreads();
    }
    if (i < n) incl[i] = s[tid];
    if (tid == 255) bsum[blockIdx.x] = s[255];
}

__global__ void k_scan_bsum(int* bsum, int nb) {   // single block, nb <= 256
    __shared__ int s[256];
    int tid = threadIdx.x;
    s[tid] = (tid < nb) ? bsum[tid] : 0;
    __syncthreads();
    for (int off = 1; off < 256; off <<= 1) {
        int t = (tid >= off) ? s[tid - off] : 0;
        __syncthreads();
        s[tid] += t;
        __syncthreads();
    }
    if (tid < nb) bsum[tid] = s[tid];
}

// row_start[i] = global exclusive scan; cursor[i] = same; row_start[n] = e
__global__ void k_scan_final(const int* __restrict__ deg, const int* __restrict__ incl,
                             const int* __restrict__ bsum, int* row_start, int* cursor,
                             int n, int e) {
    int i = blockIdx.x * 256 + threadIdx.x;
    if (i == 0) row_start[n] = e;
    if (i >= n) return;
    int base = (blockIdx.x > 0) ? bsum[blockIdx.x - 1] : 0;
    int excl = base + incl[i] - deg[i];
    row_start[i] = excl;
    cursor[i] = excl;
}

__global__ void k_csr_fill(const int* __restrict__ src, const int* __restrict__ dst,
                           const float* __restrict__ dis, int* cursor,
                           int* __restrict__ col, float* __restrict__ val, int e) {
    int i = blockIdx.x * 256 + threadIdx.x;
    if (i >= e) return;
    int s = src[i], d = dst[i];
    int pos = atomicAdd(&cursor[d], 1);
    col[pos] = s;
    val[pos] = dis[s] * dis[d];
}

// ---------------------------------------------------------------------------
// Tiled fp32 GEMM: C[n x F] = A[n x K] @ W[K x F].  BN == F.
template <int K, int F, int TN>
__global__ __launch_bounds__(256) void k_gemm(const float* __restrict__ A,
                                              const float* __restrict__ W,
                                              float* __restrict__ C, int n) {
    constexpr int BM = 128, BK = 16;
    constexpr int TCOLS = F / TN;
    constexpr int TM = BM / (256 / TCOLS);
    __shared__ float As[BK][BM];
    __shared__ float Ws[BK][F];

    const int tid = threadIdx.x;
    const int row0 = blockIdx.x * BM;
    const int tcol = (tid % TCOLS) * TN;
    const int trow = (tid / TCOLS) * TM;

    float acc[TM][TN] = {};

    for (int k0 = 0; k0 < K; k0 += BK) {
#pragma unroll
        for (int l = 0; l < (BM * BK) / (256 * 4); ++l) {
            int idx = tid + l * 256;
            int r = idx / (BK / 4);
            int kq = (idx % (BK / 4)) * 4;
            float4 v = make_float4(0.f, 0.f, 0.f, 0.f);
            int gr = row0 + r;
            if (gr < n) v = *(const float4*)&A[(size_t)gr * K + k0 + kq];
            As[kq + 0][r] = v.x; As[kq + 1][r] = v.y;
            As[kq + 2][r] = v.z; As[kq + 3][r] = v.w;
        }
#pragma unroll
        for (int l = 0; l < (BK * F) / (256 * 4); ++l) {
            int idx = tid + l * 256;
            int k = idx / (F / 4);
            int c = (idx % (F / 4)) * 4;
            *(float4*)&Ws[k][c] = *(const float4*)&W[(size_t)(k0 + k) * F + c];
        }
        __syncthreads();
#pragma unroll
        for (int k = 0; k < BK; ++k) {
            float a[TM], w[TN];
#pragma unroll
            for (int i = 0; i < TM; ++i) a[i] = As[k][trow + i];
#pragma unroll
            for (int j = 0; j < TN; ++j) w[j] = Ws[k][tcol + j];
#pragma unroll
            for (int i = 0; i < TM; ++i)
#pragma unroll
                for (int j = 0; j < TN; ++j) acc[i][j] += a[i] * w[j];
        }
        __syncthreads();
    }
#pragma unroll
    for (int i = 0; i < TM; ++i) {
        int gr = row0 + trow + i;
        if (gr < n) {
#pragma unroll
            for (int j = 0; j < TN; j += 4)
                *(float4*)&C[(size_t)gr * F + tcol + j] = *(float4*)&acc[i][j];
        }
    }
}

// ---------------------------------------------------------------------------
// Gather F=128: one wave per node, lane holds float2. Fused bias (+relu).
template <bool RELU>
__global__ __launch_bounds__(256) void k_gather128(
        const int* __restrict__ rs, const int* __restrict__ col,
        const float* __restrict__ val, const float* __restrict__ dis,
        const float* __restrict__ h, const float* __restrict__ bias,
        float* __restrict__ out, int n) {
    int node = (blockIdx.x * 256 + threadIdx.x) >> 6;
    int lane = threadIdx.x & 63;
    if (node >= n) return;
    int c = lane * 2;
    float di = dis[node];
    float2 hv = *(const float2*)&h[(size_t)node * 128 + c];
    float2 acc = make_float2(hv.x * di * di, hv.y * di * di);   // self loop
    int beg = rs[node], end = rs[node + 1];
    int j = beg;
    for (; j + 1 < end; j += 2) {
        int s0 = col[j], s1 = col[j + 1];
        float w0 = val[j], w1 = val[j + 1];
        float2 v0 = *(const float2*)&h[(size_t)s0 * 128 + c];
        float2 v1 = *(const float2*)&h[(size_t)s1 * 128 + c];
        acc.x += w0 * v0.x + w1 * v1.x;
        acc.y += w0 * v0.y + w1 * v1.y;
    }
    if (j < end) {
        int s0 = col[j]; float w0 = val[j];
        float2 v0 = *(const float2*)&h[(size_t)s0 * 128 + c];
        acc.x += w0 * v0.x; acc.y += w0 * v0.y;
    }
    acc.x += bias[c]; acc.y += bias[c + 1];
    if (RELU) { acc.x = fmaxf(acc.x, 0.f); acc.y = fmaxf(acc.y, 0.f); }
    *(float2*)&out[(size_t)node * 128 + c] = acc;
}

// Gather F=64 + fused bias + log_softmax: one wave per node, lane = feature.
__global__ __launch_bounds__(256) void k_gather64_lsm(
        const int* __restrict__ rs, const int* __restrict__ col,
        const float* __restrict__ val, const float* __restrict__ dis,
        const float* __restrict__ h, const float* __restrict__ bias,
        float* __restrict__ out, int n) {
    int node = (blockIdx.x * 256 + threadIdx.x) >> 6;
    int lane = threadIdx.x & 63;
    if (node >= n) return;
    float di = dis[node];
    float acc = h[(size_t)node * 64 + lane] * di * di;
    int beg = rs[node], end = rs[node + 1];
    for (int j = beg; j < end; ++j) {
        int s = col[j];
        acc += val[j] * h[(size_t)s * 64 + lane];
    }
    float v = acc + bias[lane];
    float m = v;
#pragma unroll
    for (int s = 32; s; s >>= 1) m = fmaxf(m, __shfl_xor(m, s));
    float e = expf(v - m);
    float sum = e;
#pragma unroll
    for (int s = 32; s; s >>= 1) sum += __shfl_xor(sum, s);
    out[(size_t)node * 64 + lane] = (v - m) - logf(sum);
}

extern "C" void kernel_launch(void* const* d_in, const int* in_sizes, int n_in,
                              void* d_out, int out_size, void* d_ws, size_t ws_size,
                              hipStream_t stream) {
    constexpr int IN = 512, HID = 128, OUT = 64;
    const float* feats = (const float*)d_in[0];
    const int*   adj   = (const int*)d_in[1];
    const float* W1 = (const float*)d_in[2];
    const float* b1 = (const float*)d_in[3];
    const float* W2 = (const float*)d_in[4];
    const float* b2 = (const float*)d_in[5];
    const float* W3 = (const float*)d_in[6];
    const float* b3 = (const float*)d_in[7];
    float* out = (float*)d_out;

    const int n = in_sizes[0] / IN;      // 50000
    const int e = in_sizes[1] / 2;       // 800000
    const int* srcp = adj;
    const int* dstp = adj + e;

    // workspace layout
    char* ws = (char*)d_ws;
    int*   deg   = (int*)ws;                 ws += (size_t)n * 4;
    float* dis   = (float*)ws;               ws += (size_t)n * 4;
    int*   incl  = (int*)ws;                 ws += (size_t)n * 4;
    int*   bsum  = (int*)ws;                 ws += 256 * 4;
    int*   rs    = (int*)ws;                 ws += (size_t)(n + 1) * 4;
    int*   curs  = (int*)ws;                 ws += (size_t)n * 4;
    int*   col   = (int*)ws;                 ws += (size_t)e * 4;
    float* val   = (float*)ws;               ws += (size_t)e * 4;
    float* bufh  = (float*)ws;               ws += (size_t)n * HID * 4;
    float* bufx  = (float*)ws;               ws += (size_t)n * HID * 4;

    const int nb_n = (n + 255) / 256;
    const int nb_e = (e + 255) / 256;
    const int nb_g = (n + 127) / 128;        // GEMM blocks
    const int nb_w = (n * 64 + 255) / 256;   // 1 wave/node kernels

    // ---- build CSR (by dst) + symmetric norm
    k_zero_i32<<<nb_n, 256, 0, stream>>>(deg, n);
    k_deg_count<<<nb_e, 256, 0, stream>>>(dstp, deg, e);
    k_dis<<<nb_n, 256, 0, stream>>>(deg, dis, n);
    k_scan_block<<<nb_n, 256, 0, stream>>>(deg, incl, bsum, n);
    k_scan_bsum<<<1, 256, 0, stream>>>(bsum, nb_n);
    k_scan_final<<<nb_n, 256, 0, stream>>>(deg, incl, bsum, rs, curs, n, e);
    k_csr_fill<<<nb_e, 256, 0, stream>>>(srcp, dstp, dis, curs, col, val, e);

    // ---- layer 1: 512 -> 128, gather + bias + relu
    k_gemm<IN, HID, 8><<<nb_g, 256, 0, stream>>>(feats, W1, bufh, n);
    k_gather128<true><<<nb_w, 256, 0, stream>>>(rs, col, val, dis, bufh, b1, bufx, n);

    // ---- layer 2: 128 -> 128, gather + bias + relu
    k_gemm<HID, HID, 8><<<nb_g, 256, 0, stream>>>(bufx, W2, bufh, n);
    k_gather128<true><<<nb_w, 256, 0, stream>>>(rs, col, val, dis, bufh, b2, bufx, n);

    // ---- layer 3: 128 -> 64, gather + bias + log_softmax
    k_gemm<HID, OUT, 4><<<nb_g, 256, 0, stream>>>(bufx, W3, bufh, n);
    k_gather64_lsm<<<nb_w, 256, 0, stream>>>(rs, col, val, dis, bufh, b3, out, n);
}

// Round 3
// 510.171 us; speedup vs baseline: 7.3482x; 1.3557x over previous
//
#include <hip/hip_runtime.h>
#include <hip/hip_bf16.h>
#include <math.h>

// ---------------------------------------------------------------------------
// GCN 3-layer forward. R3: bf16 MFMA GEMMs (16x16x32), bf16 h/x buffers to
// halve gather traffic, fp32 accumulation everywhere.
// ---------------------------------------------------------------------------

using short8  = __attribute__((ext_vector_type(8))) short;
using floatx4 = __attribute__((ext_vector_type(4))) float;

__device__ inline float bf2f(unsigned int u16) {
    union { unsigned int i; float f; } x; x.i = u16 << 16; return x.f;
}
__device__ inline unsigned short f2bf(float f) {
    union { float f; unsigned int i; } x; x.f = f;
    unsigned int lsb = (x.i >> 16) & 1u;
    return (unsigned short)((x.i + 0x7fffu + lsb) >> 16);
}

// ---------------- CSR build ----------------
__global__ void k_zero_i32(int* p, int n) {
    int i = blockIdx.x * 256 + threadIdx.x;
    if (i < n) p[i] = 0;
}

__global__ void k_deg_count(const int* __restrict__ dst, int* deg, int e) {
    int i = blockIdx.x * 256 + threadIdx.x;
    if (i < e) atomicAdd(&deg[dst[i]], 1);
}

__global__ void k_dis(const int* __restrict__ deg, float* dis, int n) {
    int i = blockIdx.x * 256 + threadIdx.x;
    if (i < n) dis[i] = rsqrtf((float)(deg[i] + 1));   // +1 self loop
}

__global__ void k_scan_block(const int* __restrict__ deg, int* incl, int* bsum, int n) {
    __shared__ int s[256];
    int tid = threadIdx.x;
    int i = blockIdx.x * 256 + tid;
    int v = (i < n) ? deg[i] : 0;
    s[tid] = v;
    __syncthreads();
    for (int off = 1; off < 256; off <<= 1) {
        int t = (tid >= off) ? s[tid - off] : 0;
        __syncthreads();
        s[tid] += t;
        __syncthreads();
    }
    if (i < n) incl[i] = s[tid];
    if (tid == 255) bsum[blockIdx.x] = s[255];
}

__global__ void k_scan_bsum(int* bsum, int nb) {   // single block, nb <= 256
    __shared__ int s[256];
    int tid = threadIdx.x;
    s[tid] = (tid < nb) ? bsum[tid] : 0;
    __syncthreads();
    for (int off = 1; off < 256; off <<= 1) {
        int t = (tid >= off) ? s[tid - off] : 0;
        __syncthreads();
        s[tid] += t;
        __syncthreads();
    }
    if (tid < nb) bsum[tid] = s[tid];
}

__global__ void k_scan_final(const int* __restrict__ deg, const int* __restrict__ incl,
                             const int* __restrict__ bsum, int* row_start, int* cursor,
                             int n, int e) {
    int i = blockIdx.x * 256 + threadIdx.x;
    if (i == 0) row_start[n] = e;
    if (i >= n) return;
    int base = (blockIdx.x > 0) ? bsum[blockIdx.x - 1] : 0;
    int excl = base + incl[i] - deg[i];
    row_start[i] = excl;
    cursor[i] = excl;
}

__global__ void k_csr_fill(const int* __restrict__ src, const int* __restrict__ dst,
                           const float* __restrict__ dis, int* cursor,
                           int* __restrict__ col, float* __restrict__ val, int e) {
    int i = blockIdx.x * 256 + threadIdx.x;
    if (i >= e) return;
    int s = src[i], d = dst[i];
    int pos = atomicAdd(&cursor[d], 1);
    col[pos] = s;
    val[pos] = dis[s] * dis[d];
}

// ---------------- W transpose + bf16 cast: Wt[f][k] = bf16(W[k][f]) --------
__global__ void k_wt(const float* __restrict__ W, unsigned short* __restrict__ Wt,
                     int K, int F) {
    int i = blockIdx.x * 256 + threadIdx.x;
    if (i >= K * F) return;
    int k = i / F, f = i % F;
    Wt[(size_t)f * K + k] = f2bf(W[i]);
}

// ---------------- MFMA GEMM: C[n x BN](bf16) = A[n x K] @ Wt^T -------------
// Wt is [BN x K] bf16 (i.e. W transposed). Block: 256 thr = 4 waves, BM=64.
// Wave w computes rows [w*16, w*16+16) x BN cols via 16x16x32 bf16 MFMA.
template <int K, int BN, bool A_BF16>
__global__ __launch_bounds__(256) void k_gemm_mfma(const void* __restrict__ Av,
                                                   const unsigned short* __restrict__ Wt,
                                                   unsigned short* __restrict__ C, int n) {
    constexpr int BM = 64, BK = 64;
    constexpr int NT = BN / 16;                 // col tiles per wave
    __shared__ unsigned short As[BM][BK];       // 8 KB
    __shared__ unsigned short Bs[BN][BK];       // 16 KB (BN=128) / 8 KB (BN=64)

    const int tid = threadIdx.x;
    const int row0 = blockIdx.x * BM;
    const int wv = tid >> 6;
    const int lane = tid & 63;
    const int m = lane & 15;
    const int quad = lane >> 4;

    floatx4 acc[NT] = {};

    for (int k0 = 0; k0 < K; k0 += BK) {
        // ---- stage A tile (convert fp32->bf16 if needed)
        if constexpr (A_BF16) {
            const unsigned short* A = (const unsigned short*)Av;
#pragma unroll
            for (int l = 0; l < (BM * BK) / (256 * 8); ++l) {   // 16B chunks
                int id = tid + l * 256;
                int r = id / (BK / 8);
                int p = id % (BK / 8);
                int gr = row0 + r;
                uint4 v = make_uint4(0, 0, 0, 0);
                if (gr < n) v = *(const uint4*)&A[(size_t)gr * K + k0 + p * 8];
                *(uint4*)&As[r][p * 8] = v;
            }
        } else {
            const float* A = (const float*)Av;
#pragma unroll
            for (int l = 0; l < (BM * BK) / (256 * 4); ++l) {   // float4 chunks
                int id = tid + l * 256;
                int r = id / (BK / 4);
                int p = id % (BK / 4);
                int gr = row0 + r;
                float4 v = make_float4(0.f, 0.f, 0.f, 0.f);
                if (gr < n) v = *(const float4*)&A[(size_t)gr * K + k0 + p * 4];
                ushort4 u;
                u.x = f2bf(v.x); u.y = f2bf(v.y); u.z = f2bf(v.z); u.w = f2bf(v.w);
                *(ushort4*)&As[r][p * 4] = u;
            }
        }
        // ---- stage B tile (already bf16, already [n][k] layout)
#pragma unroll
        for (int l = 0; l < (BN * BK) / (256 * 8); ++l) {
            int id = tid + l * 256;
            int nn = id / (BK / 8);
            int p = id % (BK / 8);
            *(uint4*)&Bs[nn][p * 8] = *(const uint4*)&Wt[(size_t)nn * K + k0 + p * 8];
        }
        __syncthreads();

        short8 a0 = *(short8*)&As[wv * 16 + m][quad * 8];
        short8 a1 = *(short8*)&As[wv * 16 + m][32 + quad * 8];
#pragma unroll
        for (int t = 0; t < NT; ++t) {
            short8 b0 = *(short8*)&Bs[t * 16 + m][quad * 8];
            short8 b1 = *(short8*)&Bs[t * 16 + m][32 + quad * 8];
            acc[t] = __builtin_amdgcn_mfma_f32_16x16x32_bf16(a0, b0, acc[t], 0, 0, 0);
            acc[t] = __builtin_amdgcn_mfma_f32_16x16x32_bf16(a1, b1, acc[t], 0, 0, 0);
        }
        __syncthreads();
    }

    // ---- epilogue: C/D layout col=lane&15, row=quad*4+reg
#pragma unroll
    for (int t = 0; t < NT; ++t) {
        int cc = t * 16 + m;
#pragma unroll
        for (int r = 0; r < 4; ++r) {
            int grow = row0 + wv * 16 + quad * 4 + r;
            if (grow < n) C[(size_t)grow * BN + cc] = f2bf(acc[t][r]);
        }
    }
}

// ---------------- Gather F=128 (bf16 h/out), fused bias(+relu) -------------
template <bool RELU>
__global__ __launch_bounds__(256) void k_gather128(
        const int* __restrict__ rs, const int* __restrict__ col,
        const float* __restrict__ val, const float* __restrict__ dis,
        const unsigned short* __restrict__ h, const float* __restrict__ bias,
        unsigned short* __restrict__ out, int n) {
    int node = (blockIdx.x * 256 + threadIdx.x) >> 6;
    int lane = threadIdx.x & 63;
    if (node >= n) return;
    int c = lane * 2;
    float di = dis[node];
    unsigned int hv = *(const unsigned int*)&h[(size_t)node * 128 + c];
    float ax = bf2f(hv & 0xffffu) * di * di;
    float ay = bf2f(hv >> 16) * di * di;
    int beg = rs[node], end = rs[node + 1];
    int j = beg;
    for (; j + 1 < end; j += 2) {
        int s0 = col[j], s1 = col[j + 1];
        float w0 = val[j], w1 = val[j + 1];
        unsigned int v0 = *(const unsigned int*)&h[(size_t)s0 * 128 + c];
        unsigned int v1 = *(const unsigned int*)&h[(size_t)s1 * 128 + c];
        ax += w0 * bf2f(v0 & 0xffffu) + w1 * bf2f(v1 & 0xffffu);
        ay += w0 * bf2f(v0 >> 16) + w1 * bf2f(v1 >> 16);
    }
    if (j < end) {
        int s0 = col[j]; float w0 = val[j];
        unsigned int v0 = *(const unsigned int*)&h[(size_t)s0 * 128 + c];
        ax += w0 * bf2f(v0 & 0xffffu);
        ay += w0 * bf2f(v0 >> 16);
    }
    ax += bias[c]; ay += bias[c + 1];
    if (RELU) { ax = fmaxf(ax, 0.f); ay = fmaxf(ay, 0.f); }
    unsigned int o = (unsigned int)f2bf(ax) | ((unsigned int)f2bf(ay) << 16);
    *(unsigned int*)&out[(size_t)node * 128 + c] = o;
}

// ---------------- Gather F=64 (bf16 h) + bias + log_softmax (fp32 out) -----
__global__ __launch_bounds__(256) void k_gather64_lsm(
        const int* __restrict__ rs, const int* __restrict__ col,
        const float* __restrict__ val, const float* __restrict__ dis,
        const unsigned short* __restrict__ h, const float* __restrict__ bias,
        float* __restrict__ out, int n) {
    int node = (blockIdx.x * 256 + threadIdx.x) >> 6;
    int lane = threadIdx.x & 63;
    if (node >= n) return;
    float di = dis[node];
    float acc = bf2f(h[(size_t)node * 64 + lane]) * di * di;
    int beg = rs[node], end = rs[node + 1];
    for (int j = beg; j < end; ++j) {
        int s = col[j];
        acc += val[j] * bf2f(h[(size_t)s * 64 + lane]);
    }
    float v = acc + bias[lane];
    float mm = v;
#pragma unroll
    for (int s = 32; s; s >>= 1) mm = fmaxf(mm, __shfl_xor(mm, s));
    float e = expf(v - mm);
    float sum = e;
#pragma unroll
    for (int s = 32; s; s >>= 1) sum += __shfl_xor(sum, s);
    out[(size_t)node * 64 + lane] = (v - mm) - logf(sum);
}

extern "C" void kernel_launch(void* const* d_in, const int* in_sizes, int n_in,
                              void* d_out, int out_size, void* d_ws, size_t ws_size,
                              hipStream_t stream) {
    constexpr int IN = 512, HID = 128, OUT = 64;
    const float* feats = (const float*)d_in[0];
    const int*   adj   = (const int*)d_in[1];
    const float* W1 = (const float*)d_in[2];
    const float* b1 = (const float*)d_in[3];
    const float* W2 = (const float*)d_in[4];
    const float* b2 = (const float*)d_in[5];
    const float* W3 = (const float*)d_in[6];
    const float* b3 = (const float*)d_in[7];
    float* out = (float*)d_out;

    const int n = in_sizes[0] / IN;      // 50000
    const int e = in_sizes[1] / 2;       // 800000
    const int* srcp = adj;
    const int* dstp = adj + e;

    // workspace layout
    char* ws = (char*)d_ws;
    int*   deg  = (int*)ws;                    ws += (size_t)n * 4;
    float* dis  = (float*)ws;                  ws += (size_t)n * 4;
    int*   incl = (int*)ws;                    ws += (size_t)n * 4;
    int*   bsum = (int*)ws;                    ws += 256 * 4;
    int*   rs   = (int*)ws;                    ws += (size_t)(n + 1) * 4 + 4;
    int*   curs = (int*)ws;                    ws += (size_t)n * 4;
    int*   col  = (int*)ws;                    ws += (size_t)e * 4;
    float* val  = (float*)ws;                  ws += (size_t)e * 4;
    unsigned short* Wt1 = (unsigned short*)ws; ws += (size_t)IN * HID * 2;
    unsigned short* Wt2 = (unsigned short*)ws; ws += (size_t)HID * HID * 2;
    unsigned short* Wt3 = (unsigned short*)ws; ws += (size_t)HID * OUT * 2;
    unsigned short* hb  = (unsigned short*)ws; ws += (size_t)n * HID * 2;
    unsigned short* xb  = (unsigned short*)ws; ws += (size_t)n * HID * 2;

    const int nb_n = (n + 255) / 256;
    const int nb_e = (e + 255) / 256;
    const int nb_g = (n + 63) / 64;          // MFMA GEMM blocks (BM=64)
    const int nb_w = (n * 64 + 255) / 256;   // 1 wave/node kernels

    // ---- build CSR (by dst) + symmetric norm
    k_zero_i32<<<nb_n, 256, 0, stream>>>(deg, n);
    k_deg_count<<<nb_e, 256, 0, stream>>>(dstp, deg, e);
    k_dis<<<nb_n, 256, 0, stream>>>(deg, dis, n);
    k_scan_block<<<nb_n, 256, 0, stream>>>(deg, incl, bsum, n);
    k_scan_bsum<<<1, 256, 0, stream>>>(bsum, nb_n);
    k_scan_final<<<nb_n, 256, 0, stream>>>(deg, incl, bsum, rs, curs, n, e);
    k_csr_fill<<<nb_e, 256, 0, stream>>>(srcp, dstp, dis, curs, col, val, e);

    // ---- weight transposes (fp32 -> bf16, [K][F] -> [F][K])
    k_wt<<<(IN * HID + 255) / 256, 256, 0, stream>>>(W1, Wt1, IN, HID);
    k_wt<<<(HID * HID + 255) / 256, 256, 0, stream>>>(W2, Wt2, HID, HID);
    k_wt<<<(HID * OUT + 255) / 256, 256, 0, stream>>>(W3, Wt3, HID, OUT);

    // ---- layer 1: 512 -> 128, gather + bias + relu
    k_gemm_mfma<IN, HID, false><<<nb_g, 256, 0, stream>>>(feats, Wt1, hb, n);
    k_gather128<true><<<nb_w, 256, 0, stream>>>(rs, col, val, dis, hb, b1, xb, n);

    // ---- layer 2: 128 -> 128, gather + bias + relu
    k_gemm_mfma<HID, HID, true><<<nb_g, 256, 0, stream>>>(xb, Wt2, hb, n);
    k_gather128<true><<<nb_w, 256, 0, stream>>>(rs, col, val, dis, hb, b2, xb, n);

    // ---- layer 3: 128 -> 64, gather + bias + log_softmax
    k_gemm_mfma<HID, OUT, true><<<nb_g, 256, 0, stream>>>(xb, Wt3, hb, n);
    k_gather64_lsm<<<nb_w, 256, 0, stream>>>(rs, col, val, dis, hb, b3, out, n);
}

// Round 4
// 441.786 us; speedup vs baseline: 8.4857x; 1.1548x over previous
//
#include <hip/hip_runtime.h>
#include <hip/hip_bf16.h>
#include <math.h>

// ---------------------------------------------------------------------------
// GCN 3-layer forward. R4: gather loops restructured for 4-way MLP
// (index-clamped predicated unroll -> 4 independent h-row loads in flight).
// ---------------------------------------------------------------------------

using short8  = __attribute__((ext_vector_type(8))) short;
using floatx4 = __attribute__((ext_vector_type(4))) float;

__device__ inline float bf2f(unsigned int u16) {
    union { unsigned int i; float f; } x; x.i = u16 << 16; return x.f;
}
__device__ inline unsigned short f2bf(float f) {
    union { float f; unsigned int i; } x; x.f = f;
    unsigned int lsb = (x.i >> 16) & 1u;
    return (unsigned short)((x.i + 0x7fffu + lsb) >> 16);
}

// ---------------- CSR build ----------------
__global__ void k_zero_i32(int* p, int n) {
    int i = blockIdx.x * 256 + threadIdx.x;
    if (i < n) p[i] = 0;
}

__global__ void k_deg_count(const int* __restrict__ dst, int* deg, int e) {
    int i = blockIdx.x * 256 + threadIdx.x;
    if (i < e) atomicAdd(&deg[dst[i]], 1);
}

__global__ void k_dis(const int* __restrict__ deg, float* dis, int n) {
    int i = blockIdx.x * 256 + threadIdx.x;
    if (i < n) dis[i] = rsqrtf((float)(deg[i] + 1));   // +1 self loop
}

__global__ void k_scan_block(const int* __restrict__ deg, int* incl, int* bsum, int n) {
    __shared__ int s[256];
    int tid = threadIdx.x;
    int i = blockIdx.x * 256 + tid;
    int v = (i < n) ? deg[i] : 0;
    s[tid] = v;
    __syncthreads();
    for (int off = 1; off < 256; off <<= 1) {
        int t = (tid >= off) ? s[tid - off] : 0;
        __syncthreads();
        s[tid] += t;
        __syncthreads();
    }
    if (i < n) incl[i] = s[tid];
    if (tid == 255) bsum[blockIdx.x] = s[255];
}

__global__ void k_scan_bsum(int* bsum, int nb) {   // single block, nb <= 256
    __shared__ int s[256];
    int tid = threadIdx.x;
    s[tid] = (tid < nb) ? bsum[tid] : 0;
    __syncthreads();
    for (int off = 1; off < 256; off <<= 1) {
        int t = (tid >= off) ? s[tid - off] : 0;
        __syncthreads();
        s[tid] += t;
        __syncthreads();
    }
    if (tid < nb) bsum[tid] = s[tid];
}

__global__ void k_scan_final(const int* __restrict__ deg, const int* __restrict__ incl,
                             const int* __restrict__ bsum, int* row_start, int* cursor,
                             int n, int e) {
    int i = blockIdx.x * 256 + threadIdx.x;
    if (i == 0) row_start[n] = e;
    if (i >= n) return;
    int base = (blockIdx.x > 0) ? bsum[blockIdx.x - 1] : 0;
    int excl = base + incl[i] - deg[i];
    row_start[i] = excl;
    cursor[i] = excl;
}

__global__ void k_csr_fill(const int* __restrict__ src, const int* __restrict__ dst,
                           const float* __restrict__ dis, int* cursor,
                           int* __restrict__ col, float* __restrict__ val, int e) {
    int i = blockIdx.x * 256 + threadIdx.x;
    if (i >= e) return;
    int s = src[i], d = dst[i];
    int pos = atomicAdd(&cursor[d], 1);
    col[pos] = s;
    val[pos] = dis[s] * dis[d];
}

// ---------------- W transpose + bf16 cast: Wt[f][k] = bf16(W[k][f]) --------
__global__ void k_wt(const float* __restrict__ W, unsigned short* __restrict__ Wt,
                     int K, int F) {
    int i = blockIdx.x * 256 + threadIdx.x;
    if (i >= K * F) return;
    int k = i / F, f = i % F;
    Wt[(size_t)f * K + k] = f2bf(W[i]);
}

// ---------------- MFMA GEMM: C[n x BN](bf16) = A[n x K] @ Wt^T -------------
template <int K, int BN, bool A_BF16>
__global__ __launch_bounds__(256) void k_gemm_mfma(const void* __restrict__ Av,
                                                   const unsigned short* __restrict__ Wt,
                                                   unsigned short* __restrict__ C, int n) {
    constexpr int BM = 64, BK = 64;
    constexpr int NT = BN / 16;                 // col tiles per wave
    __shared__ unsigned short As[BM][BK];       // 8 KB
    __shared__ unsigned short Bs[BN][BK];       // 16 KB (BN=128) / 8 KB (BN=64)

    const int tid = threadIdx.x;
    const int row0 = blockIdx.x * BM;
    const int wv = tid >> 6;
    const int lane = tid & 63;
    const int m = lane & 15;
    const int quad = lane >> 4;

    floatx4 acc[NT] = {};

    for (int k0 = 0; k0 < K; k0 += BK) {
        if constexpr (A_BF16) {
            const unsigned short* A = (const unsigned short*)Av;
#pragma unroll
            for (int l = 0; l < (BM * BK) / (256 * 8); ++l) {
                int id = tid + l * 256;
                int r = id / (BK / 8);
                int p = id % (BK / 8);
                int gr = row0 + r;
                uint4 v = make_uint4(0, 0, 0, 0);
                if (gr < n) v = *(const uint4*)&A[(size_t)gr * K + k0 + p * 8];
                *(uint4*)&As[r][p * 8] = v;
            }
        } else {
            const float* A = (const float*)Av;
#pragma unroll
            for (int l = 0; l < (BM * BK) / (256 * 4); ++l) {
                int id = tid + l * 256;
                int r = id / (BK / 4);
                int p = id % (BK / 4);
                int gr = row0 + r;
                float4 v = make_float4(0.f, 0.f, 0.f, 0.f);
                if (gr < n) v = *(const float4*)&A[(size_t)gr * K + k0 + p * 4];
                ushort4 u;
                u.x = f2bf(v.x); u.y = f2bf(v.y); u.z = f2bf(v.z); u.w = f2bf(v.w);
                *(ushort4*)&As[r][p * 4] = u;
            }
        }
#pragma unroll
        for (int l = 0; l < (BN * BK) / (256 * 8); ++l) {
            int id = tid + l * 256;
            int nn = id / (BK / 8);
            int p = id % (BK / 8);
            *(uint4*)&Bs[nn][p * 8] = *(const uint4*)&Wt[(size_t)nn * K + k0 + p * 8];
        }
        __syncthreads();

        short8 a0 = *(short8*)&As[wv * 16 + m][quad * 8];
        short8 a1 = *(short8*)&As[wv * 16 + m][32 + quad * 8];
#pragma unroll
        for (int t = 0; t < NT; ++t) {
            short8 b0 = *(short8*)&Bs[t * 16 + m][quad * 8];
            short8 b1 = *(short8*)&Bs[t * 16 + m][32 + quad * 8];
            acc[t] = __builtin_amdgcn_mfma_f32_16x16x32_bf16(a0, b0, acc[t], 0, 0, 0);
            acc[t] = __builtin_amdgcn_mfma_f32_16x16x32_bf16(a1, b1, acc[t], 0, 0, 0);
        }
        __syncthreads();
    }

#pragma unroll
    for (int t = 0; t < NT; ++t) {
        int cc = t * 16 + m;
#pragma unroll
        for (int r = 0; r < 4; ++r) {
            int grow = row0 + wv * 16 + quad * 4 + r;
            if (grow < n) C[(size_t)grow * BN + cc] = f2bf(acc[t][r]);
        }
    }
}

// ---------------- Gather F=128 (bf16 h/out), fused bias(+relu) -------------
// 4-way MLP: every round issues 4 independent h-row loads (clamped index,
// zeroed weight for out-of-range), no serial tail loop.
template <bool RELU>
__global__ __launch_bounds__(256) void k_gather128(
        const int* __restrict__ rs, const int* __restrict__ col,
        const float* __restrict__ val, const float* __restrict__ dis,
        const unsigned short* __restrict__ h, const float* __restrict__ bias,
        unsigned short* __restrict__ out, int n) {
    int node = (blockIdx.x * 256 + threadIdx.x) >> 6;
    int lane = threadIdx.x & 63;
    if (node >= n) return;
    int c = lane * 2;
    float di = dis[node];
    unsigned int hv = *(const unsigned int*)&h[(size_t)node * 128 + c];
    float ax = bf2f(hv & 0xffffu) * di * di;
    float ay = bf2f(hv >> 16) * di * di;
    float bx = 0.f, by = 0.f;
    int beg = rs[node], end = rs[node + 1];
    int last = end - 1;
    for (int j = beg; j < end; j += 4) {
        int j1 = min(j + 1, last), j2 = min(j + 2, last), j3 = min(j + 3, last);
        int s0 = col[j], s1 = col[j1], s2 = col[j2], s3 = col[j3];
        float w0 = val[j];
        float w1 = (j + 1 < end) ? val[j1] : 0.f;
        float w2 = (j + 2 < end) ? val[j2] : 0.f;
        float w3 = (j + 3 < end) ? val[j3] : 0.f;
        unsigned int v0 = *(const unsigned int*)&h[(size_t)s0 * 128 + c];
        unsigned int v1 = *(const unsigned int*)&h[(size_t)s1 * 128 + c];
        unsigned int v2 = *(const unsigned int*)&h[(size_t)s2 * 128 + c];
        unsigned int v3 = *(const unsigned int*)&h[(size_t)s3 * 128 + c];
        ax += w0 * bf2f(v0 & 0xffffu) + w1 * bf2f(v1 & 0xffffu);
        ay += w0 * bf2f(v0 >> 16)     + w1 * bf2f(v1 >> 16);
        bx += w2 * bf2f(v2 & 0xffffu) + w3 * bf2f(v3 & 0xffffu);
        by += w2 * bf2f(v2 >> 16)     + w3 * bf2f(v3 >> 16);
    }
    ax += bx + bias[c]; ay += by + bias[c + 1];
    if (RELU) { ax = fmaxf(ax, 0.f); ay = fmaxf(ay, 0.f); }
    unsigned int o = (unsigned int)f2bf(ax) | ((unsigned int)f2bf(ay) << 16);
    *(unsigned int*)&out[(size_t)node * 128 + c] = o;
}

// ---------------- Gather F=64 (bf16 h) + bias + log_softmax (fp32 out) -----
__global__ __launch_bounds__(256) void k_gather64_lsm(
        const int* __restrict__ rs, const int* __restrict__ col,
        const float* __restrict__ val, const float* __restrict__ dis,
        const unsigned short* __restrict__ h, const float* __restrict__ bias,
        float* __restrict__ out, int n) {
    int node = (blockIdx.x * 256 + threadIdx.x) >> 6;
    int lane = threadIdx.x & 63;
    if (node >= n) return;
    float di = dis[node];
    float a0 = bf2f(h[(size_t)node * 64 + lane]) * di * di;
    float a1 = 0.f;
    int beg = rs[node], end = rs[node + 1];
    int last = end - 1;
    for (int j = beg; j < end; j += 4) {
        int j1 = min(j + 1, last), j2 = min(j + 2, last), j3 = min(j + 3, last);
        int s0 = col[j], s1 = col[j1], s2 = col[j2], s3 = col[j3];
        float w0 = val[j];
        float w1 = (j + 1 < end) ? val[j1] : 0.f;
        float w2 = (j + 2 < end) ? val[j2] : 0.f;
        float w3 = (j + 3 < end) ? val[j3] : 0.f;
        float h0 = bf2f(h[(size_t)s0 * 64 + lane]);
        float h1 = bf2f(h[(size_t)s1 * 64 + lane]);
        float h2 = bf2f(h[(size_t)s2 * 64 + lane]);
        float h3 = bf2f(h[(size_t)s3 * 64 + lane]);
        a0 += w0 * h0 + w1 * h1;
        a1 += w2 * h2 + w3 * h3;
    }
    float v = a0 + a1 + bias[lane];
    float mm = v;
#pragma unroll
    for (int s = 32; s; s >>= 1) mm = fmaxf(mm, __shfl_xor(mm, s));
    float e = expf(v - mm);
    float sum = e;
#pragma unroll
    for (int s = 32; s; s >>= 1) sum += __shfl_xor(sum, s);
    out[(size_t)node * 64 + lane] = (v - mm) - logf(sum);
}

extern "C" void kernel_launch(void* const* d_in, const int* in_sizes, int n_in,
                              void* d_out, int out_size, void* d_ws, size_t ws_size,
                              hipStream_t stream) {
    constexpr int IN = 512, HID = 128, OUT = 64;
    const float* feats = (const float*)d_in[0];
    const int*   adj   = (const int*)d_in[1];
    const float* W1 = (const float*)d_in[2];
    const float* b1 = (const float*)d_in[3];
    const float* W2 = (const float*)d_in[4];
    const float* b2 = (const float*)d_in[5];
    const float* W3 = (const float*)d_in[6];
    const float* b3 = (const float*)d_in[7];
    float* out = (float*)d_out;

    const int n = in_sizes[0] / IN;      // 50000
    const int e = in_sizes[1] / 2;       // 800000
    const int* srcp = adj;
    const int* dstp = adj + e;

    // workspace layout
    char* ws = (char*)d_ws;
    int*   deg  = (int*)ws;                    ws += (size_t)n * 4;
    float* dis  = (float*)ws;                  ws += (size_t)n * 4;
    int*   incl = (int*)ws;                    ws += (size_t)n * 4;
    int*   bsum = (int*)ws;                    ws += 256 * 4;
    int*   rs   = (int*)ws;                    ws += (size_t)(n + 1) * 4 + 4;
    int*   curs = (int*)ws;                    ws += (size_t)n * 4;
    int*   col  = (int*)ws;                    ws += (size_t)e * 4;
    float* val  = (float*)ws;                  ws += (size_t)e * 4;
    unsigned short* Wt1 = (unsigned short*)ws; ws += (size_t)IN * HID * 2;
    unsigned short* Wt2 = (unsigned short*)ws; ws += (size_t)HID * HID * 2;
    unsigned short* Wt3 = (unsigned short*)ws; ws += (size_t)HID * OUT * 2;
    unsigned short* hb  = (unsigned short*)ws; ws += (size_t)n * HID * 2;
    unsigned short* xb  = (unsigned short*)ws; ws += (size_t)n * HID * 2;

    const int nb_n = (n + 255) / 256;
    const int nb_e = (e + 255) / 256;
    const int nb_g = (n + 63) / 64;          // MFMA GEMM blocks (BM=64)
    const int nb_w = (n * 64 + 255) / 256;   // 1 wave/node kernels

    // ---- build CSR (by dst) + symmetric norm
    k_zero_i32<<<nb_n, 256, 0, stream>>>(deg, n);
    k_deg_count<<<nb_e, 256, 0, stream>>>(dstp, deg, e);
    k_dis<<<nb_n, 256, 0, stream>>>(deg, dis, n);
    k_scan_block<<<nb_n, 256, 0, stream>>>(deg, incl, bsum, n);
    k_scan_bsum<<<1, 256, 0, stream>>>(bsum, nb_n);
    k_scan_final<<<nb_n, 256, 0, stream>>>(deg, incl, bsum, rs, curs, n, e);
    k_csr_fill<<<nb_e, 256, 0, stream>>>(srcp, dstp, dis, curs, col, val, e);

    // ---- weight transposes (fp32 -> bf16, [K][F] -> [F][K])
    k_wt<<<(IN * HID + 255) / 256, 256, 0, stream>>>(W1, Wt1, IN, HID);
    k_wt<<<(HID * HID + 255) / 256, 256, 0, stream>>>(W2, Wt2, HID, HID);
    k_wt<<<(HID * OUT + 255) / 256, 256, 0, stream>>>(W3, Wt3, HID, OUT);

    // ---- layer 1: 512 -> 128, gather + bias + relu
    k_gemm_mfma<IN, HID, false><<<nb_g, 256, 0, stream>>>(feats, Wt1, hb, n);
    k_gather128<true><<<nb_w, 256, 0, stream>>>(rs, col, val, dis, hb, b1, xb, n);

    // ---- layer 2: 128 -> 128, gather + bias + relu
    k_gemm_mfma<HID, HID, true><<<nb_g, 256, 0, stream>>>(xb, Wt2, hb, n);
    k_gather128<true><<<nb_w, 256, 0, stream>>>(rs, col, val, dis, hb, b2, xb, n);

    // ---- layer 3: 128 -> 64, gather + bias + log_softmax
    k_gemm_mfma<HID, OUT, true><<<nb_g, 256, 0, stream>>>(xb, Wt3, hb, n);
    k_gather64_lsm<<<nb_w, 256, 0, stream>>>(rs, col, val, dis, hb, b3, out, n);
}